// Round 15
// baseline (1141.528 us; speedup 1.0000x reference)
//
#include <hip/hip_runtime.h>
#include <stdint.h>

typedef _Float16 f16;
typedef _Float16 h2v __attribute__((ext_vector_type(2)));
typedef _Float16 F16x8 __attribute__((ext_vector_type(8)));
typedef float F32x4 __attribute__((ext_vector_type(4)));

#define MFMA16(a,b,c) __builtin_amdgcn_mfma_f32_16x16x32_f16((a),(b),(c),0,0,0)
#define S12f 2.8853900817779268f    // 2*log2(e): folded into W1,W2,b1,b2
#define SABf (-1.4426950408889634f) // -log2(e): folded into Wa,Wb,ba,bb

// builtin only (inline-asm v_exp_f32 lacks TRANS hazard handling; r6/r7 failures)
static __device__ __forceinline__ float exp2f_b(float x){ return __builtin_amdgcn_exp2f(x); }

// 4-trans act: out = 1 - 2*((E2+1)(1+es) - (E2-E1)) / ((E1+1)(E2+1)(1+es))
static __device__ __forceinline__ f16 cfc_act(F32x4 a){
  float E1=exp2f_b(a[0]), E2=exp2f_b(a[1]), es=exp2f_b(a[2]+a[3]);
  float t1=E1+1.f, u=(E2+1.f)*(1.f+es);
  float num=u-(E2-E1);
  float r=__builtin_amdgcn_rcpf(t1*u);
  return (f16)(1.f-2.f*num*r);
}
// frag-interleaved layout: value (k,b) at (k>>3)*128 + b*8 + (k&7)
static __device__ __forceinline__ int fidx(int k,int b){ return ((k>>3)<<7)+(b<<3)+(k&7); }

// tick barrier WITHOUT vmcnt(0) drain: LDS ordering needs only lgkmcnt(0);
// the per-tick global stores (d_out streaming) are fire-and-forget and must
// NOT be drained at the barrier (full __syncthreads costs ~300+ cyc/tick here).
static __device__ __forceinline__ void tick_barrier(){
  asm volatile("s_waitcnt lgkmcnt(0)" ::: "memory");
  __builtin_amdgcn_s_barrier();
}

// ---------------- prep (byte-identical to r8/r11/r12/r13/r14's validated version) ----------------
__global__ __launch_bounds__(256) void cfc_prep(
    const float* __restrict__ W10,const float* __restrict__ W20,const float* __restrict__ Wa0,const float* __restrict__ Wb0,
    const float* __restrict__ b10,const float* __restrict__ b20,const float* __restrict__ ba0,const float* __restrict__ bb0,
    const int* __restrict__ M0,
    const float* __restrict__ W11,const float* __restrict__ W21,const float* __restrict__ Wa1,const float* __restrict__ Wb1,
    const float* __restrict__ b11,const float* __restrict__ b21,const float* __restrict__ ba1,const float* __restrict__ bb1,
    const int* __restrict__ M1,
    const float* __restrict__ W12,const float* __restrict__ W22,const float* __restrict__ Wa2,const float* __restrict__ Wb2,
    const float* __restrict__ b12,const float* __restrict__ b22,const float* __restrict__ ba2,const float* __restrict__ bb2,
    const int* __restrict__ M2,
    const float* __restrict__ Wo, f16* __restrict__ ws)
{
  int idx=blockIdx.x*256+threadIdx.x;
  if(idx>=21312) return;
  int tile=idx>>6, lane=idx&63, ml=lane&15, grp=lane>>4;
  F16x8 fr;
  if(tile<329){
    int rt,kt,c,lay;
    const float *w1,*w2,*wa,*wb,*c1,*c2,*ca,*cb; const int* M;
    if(tile<116){ rt=tile>>2; kt=tile&3; c=117; lay=0;
      w1=W10;w2=W20;wa=Wa0;wb=Wb0;M=M0;c1=b10;c2=b20;ca=ba0;cb=bb0; }
    else if(tile<249){ int u=tile-116; rt=u/7; kt=u-rt*7; c=192; lay=1;
      w1=W11;w2=W21;wa=Wa1;wb=Wb1;M=M1;c1=b11;c2=b21;ca=ba1;cb=bb1; }
    else { int u=tile-249; rt=u/5; kt=u-rt*5; c=140; lay=2;
      w1=W12;w2=W22;wa=Wa2;wb=Wb2;M=M2;c1=b12;c2=b22;ca=ba2;cb=bb2; }
    int n=rt*4+(ml>>2), mat=ml&3;
    const float* W =(mat==0)?w1:(mat==1)?w2:(mat==2)?wa:wb;
    const float* Bv=(mat==0)?c1:(mat==1)?c2:(mat==2)?ca:cb;
    float sc=(mat<2)?S12f:SABf;
    int k0=kt*32+grp*8;
    #pragma unroll
    for(int j=0;j<8;++j){
      int k=k0+j; float v=0.f; int col=-1;
      if(lay==0){       if(k<116) col=1+k; else if(k==124) col=0; else if(k==125) col=-2; }
      else if(lay==1){  if(k<116) col=k; else if(k>=128 && k<204) col=116+(k-128); else if(k==125) col=-2; }
      else {            if(k<76) col=k; else if(k>=96 && k<160) col=76+(k-96); else if(k==88) col=-2; }
      if(col>=0){ v=W[n*c+col]; if(mat<2) v*=(float)M[n*c+col]; }
      else if(col==-2){ v=Bv[n]; }
      fr[j]=(f16)(v*sc);
    }
  } else {
    int u=tile-329, rt=u>>1, kt=u&1;
    int o=rt*16+ml, k0=kt*32+grp*8;
    #pragma unroll
    for(int j=0;j<8;++j) fr[j]=(f16)Wo[o*64+k0+j];
  }
  ((F16x8*)ws)[idx]=fr;
}

// ---------------- main: 32 WGs x 1024 thr (16 waves, 4/SIMD); systolic; lgkm-only tick barrier ----------------
// tick I (P=I&1, compile-time per unrolled body), all read [P^1], write [P]:
//   w0-1  mixed: 2 L1 tiles + 2 L0 tiles (shares H0 B-frags)
//   w2-6  L1 x3 ; w7-11 L0 x5 (w7,w8 stream H2[P^1] -> d_out raw h2(I-3))
//   w12-15 L2 x4 (single write to H2)
// readout deferred to cfc_ro (in-place d_out transform h2 -> y)
__global__ __launch_bounds__(1024,4) void cfc_main(
    const float* __restrict__ dtp, const float* __restrict__ hxp,
    const f16* __restrict__ ws, float* __restrict__ outp)
{
  const int tid=threadIdx.x, lane=tid&63, w=tid>>6;
  const int b_l=lane&15, g_l=lane>>4;
  const int gb0=blockIdx.x*16;
  const f16 onef=(f16)1.f;

  __shared__ alignas(16) f16 H0[2][2048];   // h0, Kpad=128 (dt@124/one@125 injected in-reg)
  __shared__ alignas(16) f16 H1[2][1536];   // h1, Kpad=96 (one@88 injected in-reg)
  __shared__ alignas(16) f16 H2[2][1024];   // h2, K=64 (also the streaming source)
  __shared__ f16 DTS[16448];                // [t][b] stride 16, rows 1024..1027 zero

  const F16x8* wsf=(const F16x8*)ws;

  // ---- init ----
  for(int i=tid;i<4096;i+=1024) ((f16*)H0)[i]=(f16)0.f;
  for(int i=tid;i<3072;i+=1024) ((f16*)H1)[i]=(f16)0.f;
  for(int i=tid;i<2048;i+=1024) ((f16*)H2)[i]=(f16)0.f;
  for(int i=tid;i<16448;i+=1024){
    int t=i>>4, b=i&15;
    DTS[i]=(t<1024)?(f16)dtp[(size_t)(gb0+b)*1024+t]:(f16)0.f;
  }
  __syncthreads();
  for(int i=tid;i<4096;i+=1024){ int b=i>>8,u=i&255; f16 v=(f16)hxp[(size_t)(gb0+b)*256+u];
    if(u<116){ H0[0][fidx(u,b)]=v; H0[1][fidx(u,b)]=v; }
    else if(u<192){ int n=u-116; H1[0][fidx(n,b)]=v; H1[1][fidx(n,b)]=v; }
    else { int n=u-192; H2[0][fidx(n,b)]=v; H2[1][fidx(n,b)]=v; }
  }
  __syncthreads();

  if(w<2){
    // ================= mixed: 2 L1 + 2 L0 =================
    F16x8 w1f[2][7], w0f[2][4];
    #pragma unroll
    for(int j=0;j<2;++j){ int rt=2*w+j;
      #pragma unroll
      for(int kt=0;kt<7;++kt) w1f[j][kt]=wsf[(116+rt*7+kt)*64+lane]; }
    #pragma unroll
    for(int m=0;m<2;++m){ int rt=2*w+m;
      #pragma unroll
      for(int kt=0;kt<4;++kt) w0f[m][kt]=wsf[(rt*4+kt)*64+lane]; }
    const int wb1a=fidx((2*w+0)*4+g_l,b_l), wb1b=fidx((2*w+1)*4+g_l,b_l);
    const int wb0a=fidx((2*w+0)*4+g_l,b_l), wb0b=fidx((2*w+1)*4+g_l,b_l);
#define MIXED_TICK(I_,P_) do{ \
      if((I_)<=1024){ \
        F32x4 a1_0,a1_1,a0_0,a0_1; \
        a1_0[0]=0.f;a1_0[1]=0.f;a1_0[2]=0.f;a1_0[3]=0.f; a1_1=a1_0; a0_0=a1_0; a0_1=a1_0; \
        _Pragma("unroll") \
        for(int kt=0;kt<4;++kt){ \
          F16x8 Af=((const F16x8*)H0[(P_)^1])[kt*64+lane]; \
          if(kt==3 && g_l==3){ Af[4]=DTS[(I_)*16+b_l]; Af[5]=onef; } \
          a1_0=MFMA16(w1f[0][kt],Af,a1_0); a1_1=MFMA16(w1f[1][kt],Af,a1_1); \
          a0_0=MFMA16(w0f[0][kt],Af,a0_0); a0_1=MFMA16(w0f[1][kt],Af,a0_1); \
        } \
        _Pragma("unroll") \
        for(int kt=0;kt<3;++kt){ \
          F16x8 Hf=((const F16x8*)H1[(P_)^1])[kt*64+lane]; \
          a1_0=MFMA16(w1f[0][4+kt],Hf,a1_0); a1_1=MFMA16(w1f[1][4+kt],Hf,a1_1); \
        } \
        if((I_)>=1){ H1[P_][wb1a]=cfc_act(a1_0); H1[P_][wb1b]=cfc_act(a1_1); } \
        if((I_)<=1023){ H0[P_][wb0a]=cfc_act(a0_0); H0[P_][wb0b]=cfc_act(a0_1); } \
      } }while(0)
    for(int I2=0;I2<1028;I2+=2){
      MIXED_TICK(I2,0);   tick_barrier();
      MIXED_TICK(I2+1,1); tick_barrier();
    }
#undef MIXED_TICK
  } else if(w<7){
    // ================= pure L1 x3 =================
    F16x8 wf[3][7];
    #pragma unroll
    for(int j=0;j<3;++j){ int rt=4+3*(w-2)+j;
      #pragma unroll
      for(int kt=0;kt<7;++kt) wf[j][kt]=wsf[(116+rt*7+kt)*64+lane]; }
    const int wb0=fidx((4+3*(w-2)+0)*4+g_l,b_l);
    const int wb1=fidx((4+3*(w-2)+1)*4+g_l,b_l);
    const int wb2=fidx((4+3*(w-2)+2)*4+g_l,b_l);
#define L1_TICK(I_,P_) do{ \
      if((I_)>=1 && (I_)<=1024){ \
        F32x4 a0,a1,a2; \
        a0[0]=0.f;a0[1]=0.f;a0[2]=0.f;a0[3]=0.f; a1=a0; a2=a0; \
        _Pragma("unroll") \
        for(int kt=0;kt<4;++kt){ \
          F16x8 Af=((const F16x8*)H0[(P_)^1])[kt*64+lane]; \
          if(kt==3 && g_l==3){ Af[4]=DTS[(I_)*16+b_l]; Af[5]=onef; } \
          a0=MFMA16(wf[0][kt],Af,a0); a1=MFMA16(wf[1][kt],Af,a1); a2=MFMA16(wf[2][kt],Af,a2); \
        } \
        _Pragma("unroll") \
        for(int kt=0;kt<3;++kt){ \
          F16x8 Hf=((const F16x8*)H1[(P_)^1])[kt*64+lane]; \
          a0=MFMA16(wf[0][4+kt],Hf,a0); a1=MFMA16(wf[1][4+kt],Hf,a1); a2=MFMA16(wf[2][4+kt],Hf,a2); \
        } \
        H1[P_][wb0]=cfc_act(a0); H1[P_][wb1]=cfc_act(a1); H1[P_][wb2]=cfc_act(a2); \
      } }while(0)
    for(int I2=0;I2<1028;I2+=2){
      L1_TICK(I2,0);   tick_barrier();
      L1_TICK(I2+1,1); tick_barrier();
    }
#undef L1_TICK
  } else if(w<12){
    // ================= pure L0 x5 (+streaming on w7,w8) =================
    F16x8 wf[5][4];
    #pragma unroll
    for(int m=0;m<5;++m){ int rt=4+5*(w-7)+m;
      #pragma unroll
      for(int kt=0;kt<4;++kt) wf[m][kt]=wsf[(rt*4+kt)*64+lane]; }
    int wbx[5];
    #pragma unroll
    for(int m=0;m<5;++m) wbx[m]=fidx((4+5*(w-7)+m)*4+g_l,b_l);
    const bool dost=(w<9);
    const int q=lane&7, bb=(lane>>3)+8*(w-7);
    char* outPtr=(char*)outp + ((size_t)(gb0+bb)*1024)*128 + q*16;
#define L0_TICK(I_,P_) do{ \
      if((I_)<=1023){ \
        F32x4 a0,a1,a2,a3,a4; \
        a0[0]=0.f;a0[1]=0.f;a0[2]=0.f;a0[3]=0.f; a1=a0; a2=a0; a3=a0; a4=a0; \
        _Pragma("unroll") \
        for(int kt=0;kt<4;++kt){ \
          F16x8 Af=((const F16x8*)H0[(P_)^1])[kt*64+lane]; \
          if(kt==3 && g_l==3){ Af[4]=DTS[(I_)*16+b_l]; Af[5]=onef; } \
          a0=MFMA16(wf[0][kt],Af,a0); a1=MFMA16(wf[1][kt],Af,a1); \
          a2=MFMA16(wf[2][kt],Af,a2); a3=MFMA16(wf[3][kt],Af,a3); \
          a4=MFMA16(wf[4][kt],Af,a4); \
        } \
        H0[P_][wbx[0]]=cfc_act(a0); H0[P_][wbx[1]]=cfc_act(a1); \
        H0[P_][wbx[2]]=cfc_act(a2); H0[P_][wbx[3]]=cfc_act(a3); \
        H0[P_][wbx[4]]=cfc_act(a4); \
      } \
      if(dost && (I_)>=3 && (I_)<=1026){ \
        F16x8 v=((const F16x8*)H2[(P_)^1])[q*16+bb]; \
        *(F16x8*)outPtr=v; outPtr+=128; \
      } }while(0)
    for(int I2=0;I2<1028;I2+=2){
      L0_TICK(I2,0);   tick_barrier();
      L0_TICK(I2+1,1); tick_barrier();
    }
#undef L0_TICK
  } else {
    // ================= L2 x4 =================
    F16x8 wc[4][5];
    #pragma unroll
    for(int j=0;j<4;++j){ int rt=4*(w-12)+j;
      #pragma unroll
      for(int kt=0;kt<5;++kt) wc[j][kt]=wsf[(249+rt*5+kt)*64+lane]; }
    int wbx[4];
    #pragma unroll
    for(int j=0;j<4;++j) wbx[j]=fidx((4*(w-12)+j)*4+g_l,b_l);
#define L2_TICK(I_,P_) do{ \
      if((I_)>=2 && (I_)<=1025){ \
        F16x8 Cf0=((const F16x8*)H1[(P_)^1])[0*64+lane]; \
        F16x8 Cf1=((const F16x8*)H1[(P_)^1])[1*64+lane]; \
        F16x8 Cf2=((const F16x8*)H1[(P_)^1])[2*64+lane]; \
        F16x8 Cf3=((const F16x8*)H2[(P_)^1])[0*64+lane]; \
        F16x8 Cf4=((const F16x8*)H2[(P_)^1])[1*64+lane]; \
        if(g_l==3) Cf2[0]=onef; \
        F32x4 a0,a1,a2,a3; \
        a0[0]=0.f;a0[1]=0.f;a0[2]=0.f;a0[3]=0.f; a1=a0; a2=a0; a3=a0; \
        a0=MFMA16(wc[0][0],Cf0,a0); a0=MFMA16(wc[0][1],Cf1,a0); a0=MFMA16(wc[0][2],Cf2,a0); \
        a0=MFMA16(wc[0][3],Cf3,a0); a0=MFMA16(wc[0][4],Cf4,a0); \
        a1=MFMA16(wc[1][0],Cf0,a1); a1=MFMA16(wc[1][1],Cf1,a1); a1=MFMA16(wc[1][2],Cf2,a1); \
        a1=MFMA16(wc[1][3],Cf3,a1); a1=MFMA16(wc[1][4],Cf4,a1); \
        a2=MFMA16(wc[2][0],Cf0,a2); a2=MFMA16(wc[2][1],Cf1,a2); a2=MFMA16(wc[2][2],Cf2,a2); \
        a2=MFMA16(wc[2][3],Cf3,a2); a2=MFMA16(wc[2][4],Cf4,a2); \
        a3=MFMA16(wc[3][0],Cf0,a3); a3=MFMA16(wc[3][1],Cf1,a3); a3=MFMA16(wc[3][2],Cf2,a3); \
        a3=MFMA16(wc[3][3],Cf3,a3); a3=MFMA16(wc[3][4],Cf4,a3); \
        H2[P_][wbx[0]]=cfc_act(a0); H2[P_][wbx[1]]=cfc_act(a1); \
        H2[P_][wbx[2]]=cfc_act(a2); H2[P_][wbx[3]]=cfc_act(a3); \
      } }while(0)
    for(int I2=0;I2<1028;I2+=2){
      L2_TICK(I2,0);   tick_barrier();
      L2_TICK(I2+1,1); tick_barrier();
    }
#undef L2_TICK
  }
}

// ---------------- post: in-place d_out transform  h2(64 f16) -> y(32 f32) per (b,t) slot ----------------
__global__ __launch_bounds__(256) void cfc_ro(
    const float* __restrict__ Wo, const float* __restrict__ bo, float* __restrict__ outp)
{
  __shared__ h2v wT[1024];   // [kp][o]
  __shared__ float bs[32];
  int tid=threadIdx.x;
  for(int i=tid;i<1024;i+=256){ int kp=i>>5,o=i&31;
    h2v v; v[0]=(f16)Wo[o*64+2*kp]; v[1]=(f16)Wo[o*64+2*kp+1]; wT[i]=v; }
  if(tid<32) bs[tid]=bo[tid];
  __syncthreads();
  size_t s=(size_t)blockIdx.x*256+tid;      // 0..524287 = b*1024+t
  float* slot=outp+s*32;
  h2v x[32];
  #pragma unroll
  for(int r=0;r<8;++r) ((F16x8*)x)[r]=((const F16x8*)slot)[r];
  float y[32];
  #pragma unroll
  for(int o=0;o<32;++o){
    float acc=bs[o];
    #pragma unroll
    for(int kp=0;kp<32;++kp) acc=__builtin_amdgcn_fdot2(x[kp],wT[kp*32+o],acc,false);
    y[o]=acc;
  }
  #pragma unroll
  for(int r=0;r<8;++r) ((float4*)slot)[r]=((const float4*)y)[r];
}

extern "C" void kernel_launch(void* const* d_in, const int* in_sizes, int n_in,
                              void* d_out, int out_size, void* d_ws, size_t ws_size,
                              hipStream_t stream)
{
  (void)in_sizes; (void)n_in; (void)out_size; (void)ws_size;
  f16* ws=(f16*)d_ws;
  cfc_prep<<<84,256,0,stream>>>(
    (const float*)d_in[2],(const float*)d_in[3],(const float*)d_in[4],(const float*)d_in[5],
    (const float*)d_in[6],(const float*)d_in[7],(const float*)d_in[8],(const float*)d_in[9],
    (const int*)d_in[10],
    (const float*)d_in[11],(const float*)d_in[12],(const float*)d_in[13],(const float*)d_in[14],
    (const float*)d_in[15],(const float*)d_in[16],(const float*)d_in[17],(const float*)d_in[18],
    (const int*)d_in[19],
    (const float*)d_in[20],(const float*)d_in[21],(const float*)d_in[22],(const float*)d_in[23],
    (const float*)d_in[24],(const float*)d_in[25],(const float*)d_in[26],(const float*)d_in[27],
    (const int*)d_in[28],
    (const float*)d_in[29], ws);
  cfc_main<<<32,1024,0,stream>>>(
    (const float*)d_in[0],(const float*)d_in[1], ws, (float*)d_out);
  cfc_ro<<<2048,256,0,stream>>>(
    (const float*)d_in[29],(const float*)d_in[30],(float*)d_out);
}

// Round 16
// 1066.834 us; speedup vs baseline: 1.0700x; 1.0700x over previous
//
#include <hip/hip_runtime.h>
#include <stdint.h>

typedef _Float16 f16;
typedef _Float16 h2v __attribute__((ext_vector_type(2)));
typedef _Float16 F16x8 __attribute__((ext_vector_type(8)));
typedef float F32x4 __attribute__((ext_vector_type(4)));

#define MFMA16(a,b,c) __builtin_amdgcn_mfma_f32_16x16x32_f16((a),(b),(c),0,0,0)
#define S12f 2.8853900817779268f    // 2*log2(e): folded into W1,W2,b1,b2
#define SABf (-1.4426950408889634f) // -log2(e): folded into Wa,Wb,ba,bb

// builtin only (inline-asm v_exp_f32 lacks TRANS hazard handling; r6/r7 failures)
static __device__ __forceinline__ float exp2f_b(float x){ return __builtin_amdgcn_exp2f(x); }

// 4-trans act: out = 1 - 2*((E2+1)(1+es) - (E2-E1)) / ((E1+1)(E2+1)(1+es))
static __device__ __forceinline__ f16 cfc_act(F32x4 a){
  float E1=exp2f_b(a[0]), E2=exp2f_b(a[1]), es=exp2f_b(a[2]+a[3]);
  float t1=E1+1.f, u=(E2+1.f)*(1.f+es);
  float num=u-(E2-E1);
  float r=__builtin_amdgcn_rcpf(t1*u);
  return (f16)(1.f-2.f*num*r);
}
// frag-interleaved layout: value (k,b) at (k>>3)*128 + b*8 + (k&7)
static __device__ __forceinline__ int fidx(int k,int b){ return ((k>>3)<<7)+(b<<3)+(k&7); }

// tick barrier WITHOUT vmcnt(0) drain (r15: neutral vs __syncthreads, kept for safety margin)
static __device__ __forceinline__ void tick_barrier(){
  asm volatile("s_waitcnt lgkmcnt(0)" ::: "memory");
  __builtin_amdgcn_s_barrier();
}

// ---------------- prep (byte-identical to r8..r15's validated version) ----------------
__global__ __launch_bounds__(256) void cfc_prep(
    const float* __restrict__ W10,const float* __restrict__ W20,const float* __restrict__ Wa0,const float* __restrict__ Wb0,
    const float* __restrict__ b10,const float* __restrict__ b20,const float* __restrict__ ba0,const float* __restrict__ bb0,
    const int* __restrict__ M0,
    const float* __restrict__ W11,const float* __restrict__ W21,const float* __restrict__ Wa1,const float* __restrict__ Wb1,
    const float* __restrict__ b11,const float* __restrict__ b21,const float* __restrict__ ba1,const float* __restrict__ bb1,
    const int* __restrict__ M1,
    const float* __restrict__ W12,const float* __restrict__ W22,const float* __restrict__ Wa2,const float* __restrict__ Wb2,
    const float* __restrict__ b12,const float* __restrict__ b22,const float* __restrict__ ba2,const float* __restrict__ bb2,
    const int* __restrict__ M2,
    const float* __restrict__ Wo, f16* __restrict__ ws)
{
  int idx=blockIdx.x*256+threadIdx.x;
  if(idx>=21312) return;
  int tile=idx>>6, lane=idx&63, ml=lane&15, grp=lane>>4;
  F16x8 fr;
  if(tile<329){
    int rt,kt,c,lay;
    const float *w1,*w2,*wa,*wb,*c1,*c2,*ca,*cb; const int* M;
    if(tile<116){ rt=tile>>2; kt=tile&3; c=117; lay=0;
      w1=W10;w2=W20;wa=Wa0;wb=Wb0;M=M0;c1=b10;c2=b20;ca=ba0;cb=bb0; }
    else if(tile<249){ int u=tile-116; rt=u/7; kt=u-rt*7; c=192; lay=1;
      w1=W11;w2=W21;wa=Wa1;wb=Wb1;M=M1;c1=b11;c2=b21;ca=ba1;cb=bb1; }
    else { int u=tile-249; rt=u/5; kt=u-rt*5; c=140; lay=2;
      w1=W12;w2=W22;wa=Wa2;wb=Wb2;M=M2;c1=b12;c2=b22;ca=ba2;cb=bb2; }
    int n=rt*4+(ml>>2), mat=ml&3;
    const float* W =(mat==0)?w1:(mat==1)?w2:(mat==2)?wa:wb;
    const float* Bv=(mat==0)?c1:(mat==1)?c2:(mat==2)?ca:cb;
    float sc=(mat<2)?S12f:SABf;
    int k0=kt*32+grp*8;
    #pragma unroll
    for(int j=0;j<8;++j){
      int k=k0+j; float v=0.f; int col=-1;
      if(lay==0){       if(k<116) col=1+k; else if(k==124) col=0; else if(k==125) col=-2; }
      else if(lay==1){  if(k<116) col=k; else if(k>=128 && k<204) col=116+(k-128); else if(k==125) col=-2; }
      else {            if(k<76) col=k; else if(k>=96 && k<160) col=76+(k-96); else if(k==88) col=-2; }
      if(col>=0){ v=W[n*c+col]; if(mat<2) v*=(float)M[n*c+col]; }
      else if(col==-2){ v=Bv[n]; }
      fr[j]=(f16)(v*sc);
    }
  } else {
    int u=tile-329, rt=u>>1, kt=u&1;
    int o=rt*16+ml, k0=kt*32+grp*8;
    #pragma unroll
    for(int j=0;j<8;++j) fr[j]=(f16)Wo[o*64+k0+j];
  }
  ((F16x8*)ws)[idx]=fr;
}

// ---------------- main: 32 WGs x 1024 thr (16 waves, 4/SIMD); systolic; VALU-trimmed ----------------
// tick I (P=I&1, compile-time parity), all read [P^1], write [P]:
//   w0-1  mixed: 2 L1 + 2 L0 ; w2-6 L1 x3 ; w7-11 L0 x5 (w7,w8 stream H2[P^1]->d_out)
//   w12-15 L2 x4 ; w15 lane<16 writes dt(I+1) into H0[P] col124
// dt@124 column: seeded at init (dt0->H0[1]), then rolling write. one@125 / one@88: static, init-once.
// acc chains start from persistent ZED register (no per-tick zero-init).
__global__ __launch_bounds__(1024,4) void cfc_main(
    const float* __restrict__ dtp, const float* __restrict__ hxp,
    const f16* __restrict__ ws, float* __restrict__ outp)
{
  const int tid=threadIdx.x, lane=tid&63, w=tid>>6;
  const int b_l=lane&15, g_l=lane>>4;
  const int gb0=blockIdx.x*16;

  __shared__ alignas(16) f16 H0[2][2048];   // h0 | dt@124 | one@125, Kpad=128
  __shared__ alignas(16) f16 H1[2][1536];   // h1 | one@88, Kpad=96
  __shared__ alignas(16) f16 H2[2][1024];   // h2, K=64 (streaming source)
  __shared__ f16 DTS[16448];                // [t][b] stride 16, rows 1024..1027 zero

  const F16x8* wsf=(const F16x8*)ws;
  F32x4 ZED; ZED[0]=0.f; ZED[1]=0.f; ZED[2]=0.f; ZED[3]=0.f;

  // ---- init ----
  for(int i=tid;i<4096;i+=1024) ((f16*)H0)[i]=(f16)0.f;
  for(int i=tid;i<3072;i+=1024) ((f16*)H1)[i]=(f16)0.f;
  for(int i=tid;i<2048;i+=1024) ((f16*)H2)[i]=(f16)0.f;
  for(int i=tid;i<16448;i+=1024){
    int t=i>>4, b=i&15;
    DTS[i]=(t<1024)?(f16)dtp[(size_t)(gb0+b)*1024+t]:(f16)0.f;
  }
  __syncthreads();
  for(int i=tid;i<4096;i+=1024){ int b=i>>8,u=i&255; f16 v=(f16)hxp[(size_t)(gb0+b)*256+u];
    if(u<116){ H0[0][fidx(u,b)]=v; H0[1][fidx(u,b)]=v; }
    else if(u<192){ int n=u-116; H1[0][fidx(n,b)]=v; H1[1][fidx(n,b)]=v; }
    else { int n=u-192; H2[0][fidx(n,b)]=v; H2[1][fidx(n,b)]=v; }
  }
  if(tid<16){
    H0[1][fidx(124,tid)]=DTS[tid];               // dt(0) for tick 0
    H0[0][fidx(125,tid)]=(f16)1.f; H0[1][fidx(125,tid)]=(f16)1.f;
    H1[0][fidx(88,tid)]=(f16)1.f;  H1[1][fidx(88,tid)]=(f16)1.f;
  }
  __syncthreads();

  if(w<2){
    // ================= mixed: 2 L1 + 2 L0 =================
    F16x8 w1f[2][7], w0f[2][4];
    #pragma unroll
    for(int j=0;j<2;++j){ int rt=2*w+j;
      #pragma unroll
      for(int kt=0;kt<7;++kt) w1f[j][kt]=wsf[(116+rt*7+kt)*64+lane]; }
    #pragma unroll
    for(int m=0;m<2;++m){ int rt=2*w+m;
      #pragma unroll
      for(int kt=0;kt<4;++kt) w0f[m][kt]=wsf[(rt*4+kt)*64+lane]; }
    const int wb1a=fidx((2*w+0)*4+g_l,b_l), wb1b=fidx((2*w+1)*4+g_l,b_l);
    const int wb0a=fidx((2*w+0)*4+g_l,b_l), wb0b=fidx((2*w+1)*4+g_l,b_l);
#define MIXED_TICK(I_,P_) do{ \
      if((I_)<=1024){ \
        F16x8 Af0=((const F16x8*)H0[(P_)^1])[0*64+lane]; \
        F16x8 Af1=((const F16x8*)H0[(P_)^1])[1*64+lane]; \
        F16x8 Af2=((const F16x8*)H0[(P_)^1])[2*64+lane]; \
        F16x8 Af3=((const F16x8*)H0[(P_)^1])[3*64+lane]; \
        F32x4 a1_0=MFMA16(w1f[0][0],Af0,ZED), a1_1=MFMA16(w1f[1][0],Af0,ZED); \
        F32x4 a0_0=MFMA16(w0f[0][0],Af0,ZED), a0_1=MFMA16(w0f[1][0],Af0,ZED); \
        a1_0=MFMA16(w1f[0][1],Af1,a1_0); a1_1=MFMA16(w1f[1][1],Af1,a1_1); \
        a0_0=MFMA16(w0f[0][1],Af1,a0_0); a0_1=MFMA16(w0f[1][1],Af1,a0_1); \
        a1_0=MFMA16(w1f[0][2],Af2,a1_0); a1_1=MFMA16(w1f[1][2],Af2,a1_1); \
        a0_0=MFMA16(w0f[0][2],Af2,a0_0); a0_1=MFMA16(w0f[1][2],Af2,a0_1); \
        a1_0=MFMA16(w1f[0][3],Af3,a1_0); a1_1=MFMA16(w1f[1][3],Af3,a1_1); \
        a0_0=MFMA16(w0f[0][3],Af3,a0_0); a0_1=MFMA16(w0f[1][3],Af3,a0_1); \
        _Pragma("unroll") \
        for(int kt=0;kt<3;++kt){ \
          F16x8 Hf=((const F16x8*)H1[(P_)^1])[kt*64+lane]; \
          a1_0=MFMA16(w1f[0][4+kt],Hf,a1_0); a1_1=MFMA16(w1f[1][4+kt],Hf,a1_1); \
        } \
        if((I_)>=1){ H1[P_][wb1a]=cfc_act(a1_0); H1[P_][wb1b]=cfc_act(a1_1); } \
        if((I_)<=1023){ H0[P_][wb0a]=cfc_act(a0_0); H0[P_][wb0b]=cfc_act(a0_1); } \
      } }while(0)
    for(int I2=0;I2<1028;I2+=2){
      MIXED_TICK(I2,0);   tick_barrier();
      MIXED_TICK(I2+1,1); tick_barrier();
    }
#undef MIXED_TICK
  } else if(w<7){
    // ================= pure L1 x3 =================
    F16x8 wf[3][7];
    #pragma unroll
    for(int j=0;j<3;++j){ int rt=4+3*(w-2)+j;
      #pragma unroll
      for(int kt=0;kt<7;++kt) wf[j][kt]=wsf[(116+rt*7+kt)*64+lane]; }
    const int wb0=fidx((4+3*(w-2)+0)*4+g_l,b_l);
    const int wb1=fidx((4+3*(w-2)+1)*4+g_l,b_l);
    const int wb2=fidx((4+3*(w-2)+2)*4+g_l,b_l);
#define L1_TICK(I_,P_) do{ \
      if((I_)>=1 && (I_)<=1024){ \
        F16x8 Af0=((const F16x8*)H0[(P_)^1])[0*64+lane]; \
        F16x8 Af1=((const F16x8*)H0[(P_)^1])[1*64+lane]; \
        F16x8 Af2=((const F16x8*)H0[(P_)^1])[2*64+lane]; \
        F16x8 Af3=((const F16x8*)H0[(P_)^1])[3*64+lane]; \
        F32x4 a0=MFMA16(wf[0][0],Af0,ZED), a1=MFMA16(wf[1][0],Af0,ZED), a2=MFMA16(wf[2][0],Af0,ZED); \
        a0=MFMA16(wf[0][1],Af1,a0); a1=MFMA16(wf[1][1],Af1,a1); a2=MFMA16(wf[2][1],Af1,a2); \
        a0=MFMA16(wf[0][2],Af2,a0); a1=MFMA16(wf[1][2],Af2,a1); a2=MFMA16(wf[2][2],Af2,a2); \
        a0=MFMA16(wf[0][3],Af3,a0); a1=MFMA16(wf[1][3],Af3,a1); a2=MFMA16(wf[2][3],Af3,a2); \
        _Pragma("unroll") \
        for(int kt=0;kt<3;++kt){ \
          F16x8 Hf=((const F16x8*)H1[(P_)^1])[kt*64+lane]; \
          a0=MFMA16(wf[0][4+kt],Hf,a0); a1=MFMA16(wf[1][4+kt],Hf,a1); a2=MFMA16(wf[2][4+kt],Hf,a2); \
        } \
        H1[P_][wb0]=cfc_act(a0); H1[P_][wb1]=cfc_act(a1); H1[P_][wb2]=cfc_act(a2); \
      } }while(0)
    for(int I2=0;I2<1028;I2+=2){
      L1_TICK(I2,0);   tick_barrier();
      L1_TICK(I2+1,1); tick_barrier();
    }
#undef L1_TICK
  } else if(w<12){
    // ================= pure L0 x5 (+streaming on w7,w8) =================
    F16x8 wf[5][4];
    #pragma unroll
    for(int m=0;m<5;++m){ int rt=4+5*(w-7)+m;
      #pragma unroll
      for(int kt=0;kt<4;++kt) wf[m][kt]=wsf[(rt*4+kt)*64+lane]; }
    int wbx[5];
    #pragma unroll
    for(int m=0;m<5;++m) wbx[m]=fidx((4+5*(w-7)+m)*4+g_l,b_l);
    const bool dost=(w<9);
    const int q=lane&7, bb=(lane>>3)+8*(w-7);
    char* outPtr=(char*)outp + ((size_t)(gb0+bb)*1024)*128 + q*16;
#define L0_TICK(I_,P_) do{ \
      if((I_)<=1023){ \
        F16x8 Af0=((const F16x8*)H0[(P_)^1])[0*64+lane]; \
        F16x8 Af1=((const F16x8*)H0[(P_)^1])[1*64+lane]; \
        F16x8 Af2=((const F16x8*)H0[(P_)^1])[2*64+lane]; \
        F16x8 Af3=((const F16x8*)H0[(P_)^1])[3*64+lane]; \
        F32x4 a0=MFMA16(wf[0][0],Af0,ZED), a1=MFMA16(wf[1][0],Af0,ZED); \
        F32x4 a2=MFMA16(wf[2][0],Af0,ZED), a3=MFMA16(wf[3][0],Af0,ZED); \
        F32x4 a4=MFMA16(wf[4][0],Af0,ZED); \
        a0=MFMA16(wf[0][1],Af1,a0); a1=MFMA16(wf[1][1],Af1,a1); \
        a2=MFMA16(wf[2][1],Af1,a2); a3=MFMA16(wf[3][1],Af1,a3); \
        a4=MFMA16(wf[4][1],Af1,a4); \
        a0=MFMA16(wf[0][2],Af2,a0); a1=MFMA16(wf[1][2],Af2,a1); \
        a2=MFMA16(wf[2][2],Af2,a2); a3=MFMA16(wf[3][2],Af2,a3); \
        a4=MFMA16(wf[4][2],Af2,a4); \
        a0=MFMA16(wf[0][3],Af3,a0); a1=MFMA16(wf[1][3],Af3,a1); \
        a2=MFMA16(wf[2][3],Af3,a2); a3=MFMA16(wf[3][3],Af3,a3); \
        a4=MFMA16(wf[4][3],Af3,a4); \
        H0[P_][wbx[0]]=cfc_act(a0); H0[P_][wbx[1]]=cfc_act(a1); \
        H0[P_][wbx[2]]=cfc_act(a2); H0[P_][wbx[3]]=cfc_act(a3); \
        H0[P_][wbx[4]]=cfc_act(a4); \
      } \
      if(dost && (I_)>=3 && (I_)<=1026){ \
        F16x8 v=((const F16x8*)H2[(P_)^1])[q*16+bb]; \
        *(F16x8*)outPtr=v; outPtr+=128; \
      } }while(0)
    for(int I2=0;I2<1028;I2+=2){
      L0_TICK(I2,0);   tick_barrier();
      L0_TICK(I2+1,1); tick_barrier();
    }
#undef L0_TICK
  } else {
    // ================= L2 x4 (+dt column writer on w15) =================
    F16x8 wc[4][5];
    #pragma unroll
    for(int j=0;j<4;++j){ int rt=4*(w-12)+j;
      #pragma unroll
      for(int kt=0;kt<5;++kt) wc[j][kt]=wsf[(249+rt*5+kt)*64+lane]; }
    int wbx[4];
    #pragma unroll
    for(int j=0;j<4;++j) wbx[j]=fidx((4*(w-12)+j)*4+g_l,b_l);
    const bool dodt=(w==15);
#define L2_TICK(I_,P_) do{ \
      if(dodt && lane<16 && (I_)<=1022) H0[P_][fidx(124,lane)]=DTS[((I_)+1)*16+lane]; \
      if((I_)>=2 && (I_)<=1025){ \
        F16x8 Cf0=((const F16x8*)H1[(P_)^1])[0*64+lane]; \
        F16x8 Cf1=((const F16x8*)H1[(P_)^1])[1*64+lane]; \
        F16x8 Cf2=((const F16x8*)H1[(P_)^1])[2*64+lane]; \
        F16x8 Cf3=((const F16x8*)H2[(P_)^1])[0*64+lane]; \
        F16x8 Cf4=((const F16x8*)H2[(P_)^1])[1*64+lane]; \
        F32x4 a0=MFMA16(wc[0][0],Cf0,ZED), a1=MFMA16(wc[1][0],Cf0,ZED); \
        F32x4 a2=MFMA16(wc[2][0],Cf0,ZED), a3=MFMA16(wc[3][0],Cf0,ZED); \
        a0=MFMA16(wc[0][1],Cf1,a0); a1=MFMA16(wc[1][1],Cf1,a1); \
        a2=MFMA16(wc[2][1],Cf1,a2); a3=MFMA16(wc[3][1],Cf1,a3); \
        a0=MFMA16(wc[0][2],Cf2,a0); a1=MFMA16(wc[1][2],Cf2,a1); \
        a2=MFMA16(wc[2][2],Cf2,a2); a3=MFMA16(wc[3][2],Cf2,a3); \
        a0=MFMA16(wc[0][3],Cf3,a0); a1=MFMA16(wc[1][3],Cf3,a1); \
        a2=MFMA16(wc[2][3],Cf3,a2); a3=MFMA16(wc[3][3],Cf3,a3); \
        a0=MFMA16(wc[0][4],Cf4,a0); a1=MFMA16(wc[1][4],Cf4,a1); \
        a2=MFMA16(wc[2][4],Cf4,a2); a3=MFMA16(wc[3][4],Cf4,a3); \
        H2[P_][wbx[0]]=cfc_act(a0); H2[P_][wbx[1]]=cfc_act(a1); \
        H2[P_][wbx[2]]=cfc_act(a2); H2[P_][wbx[3]]=cfc_act(a3); \
      } }while(0)
    for(int I2=0;I2<1028;I2+=2){
      L2_TICK(I2,0);   tick_barrier();
      L2_TICK(I2+1,1); tick_barrier();
    }
#undef L2_TICK
  }
}

// ---------------- post: in-place d_out transform  h2(64 f16) -> y(32 f32) per (b,t) slot ----------------
__global__ __launch_bounds__(256) void cfc_ro(
    const float* __restrict__ Wo, const float* __restrict__ bo, float* __restrict__ outp)
{
  __shared__ h2v wT[1024];   // [kp][o]
  __shared__ float bs[32];
  int tid=threadIdx.x;
  for(int i=tid;i<1024;i+=256){ int kp=i>>5,o=i&31;
    h2v v; v[0]=(f16)Wo[o*64+2*kp]; v[1]=(f16)Wo[o*64+2*kp+1]; wT[i]=v; }
  if(tid<32) bs[tid]=bo[tid];
  __syncthreads();
  size_t s=(size_t)blockIdx.x*256+tid;      // 0..524287 = b*1024+t
  float* slot=outp+s*32;
  h2v x[32];
  #pragma unroll
  for(int r=0;r<8;++r) ((F16x8*)x)[r]=((const F16x8*)slot)[r];
  float y[32];
  #pragma unroll
  for(int o=0;o<32;++o){
    float acc=bs[o];
    #pragma unroll
    for(int kp=0;kp<32;++kp) acc=__builtin_amdgcn_fdot2(x[kp],wT[kp*32+o],acc,false);
    y[o]=acc;
  }
  #pragma unroll
  for(int r=0;r<8;++r) ((float4*)slot)[r]=((const float4*)y)[r];
}

extern "C" void kernel_launch(void* const* d_in, const int* in_sizes, int n_in,
                              void* d_out, int out_size, void* d_ws, size_t ws_size,
                              hipStream_t stream)
{
  (void)in_sizes; (void)n_in; (void)out_size; (void)ws_size;
  f16* ws=(f16*)d_ws;
  cfc_prep<<<84,256,0,stream>>>(
    (const float*)d_in[2],(const float*)d_in[3],(const float*)d_in[4],(const float*)d_in[5],
    (const float*)d_in[6],(const float*)d_in[7],(const float*)d_in[8],(const float*)d_in[9],
    (const int*)d_in[10],
    (const float*)d_in[11],(const float*)d_in[12],(const float*)d_in[13],(const float*)d_in[14],
    (const float*)d_in[15],(const float*)d_in[16],(const float*)d_in[17],(const float*)d_in[18],
    (const int*)d_in[19],
    (const float*)d_in[20],(const float*)d_in[21],(const float*)d_in[22],(const float*)d_in[23],
    (const float*)d_in[24],(const float*)d_in[25],(const float*)d_in[26],(const float*)d_in[27],
    (const int*)d_in[28],
    (const float*)d_in[29], ws);
  cfc_main<<<32,1024,0,stream>>>(
    (const float*)d_in[0],(const float*)d_in[1], ws, (float*)d_out);
  cfc_ro<<<2048,256,0,stream>>>(
    (const float*)d_in[29],(const float*)d_in[30],(float*)d_out);
}

// Round 17
// 1039.995 us; speedup vs baseline: 1.0976x; 1.0258x over previous
//
#include <hip/hip_runtime.h>
#include <stdint.h>

typedef _Float16 f16;
typedef _Float16 h2v __attribute__((ext_vector_type(2)));
typedef _Float16 F16x4 __attribute__((ext_vector_type(4)));
typedef _Float16 F16x8 __attribute__((ext_vector_type(8)));
typedef float F32x4 __attribute__((ext_vector_type(4)));

#define MFMA16(a,b,c) __builtin_amdgcn_mfma_f32_16x16x32_f16((a),(b),(c),0,0,0)
#define S12f 2.8853900817779268f    // 2*log2(e): folded into W1,W2,b1,b2
#define SABf (-1.4426950408889634f) // -log2(e): folded into (Wa+Wb),(ba+bb)

// builtin only (inline-asm v_exp_f32 lacks TRANS hazard handling; r6/r7 failures)
static __device__ __forceinline__ float exp2f_b(float x){ return __builtin_amdgcn_exp2f(x); }

// 3-gate act: p1,p2 prescaled by 2log2e; ps = -log2e*(x@(Wa+Wb)+ba+bb)
static __device__ __forceinline__ f16 cfc_act3(float p1,float p2,float ps){
  float E1=exp2f_b(p1), E2=exp2f_b(p2), es=exp2f_b(ps);
  float t1=E1+1.f, u=(E2+1.f)*(1.f+es);
  float num=u-(E2-E1);
  float r=__builtin_amdgcn_rcpf(t1*u);
  return (f16)(1.f-2.f*num*r);
}
// frag-interleaved layout: value (k,b) at (k>>3)*128 + b*8 + (k&7)
static __device__ __forceinline__ int fidx(int k,int b){ return ((k>>3)<<7)+(b<<3)+(k&7); }

// tick barrier WITHOUT vmcnt(0) drain
static __device__ __forceinline__ void tick_barrier(){
  asm volatile("s_waitcnt lgkmcnt(0)" ::: "memory");
  __builtin_amdgcn_s_barrier();
}

// ---------------- prep: gate-major triplet tiles, Wsig=Wa+Wb folded ----------------
// A-row ml of tile (lay,nb,m) = gate-m row n=nb*16+ml (zero row if n>=h).
// tiles: L0: (nb*3+m)*4+kt            nb<8, kt<4   [0,96)
//        L1: 96+(nb*3+m)*7+kt         nb<5, kt<7   [96,201)
//        L2: 201+(nb*3+m)*5+kt        nb<4, kt<5   [201,261)
// k->col maps (unchanged from r8..r16):
//  L0: k<116->1+k | k==124->dt(col0) | k==125->bias ; L1: k<116->k | 128<=k<204->116+(k-128) | k==125->bias
//  L2: k<76->k | 96<=k<160->76+(k-96) | k==88->bias
__global__ __launch_bounds__(256) void cfc_prep(
    const float* __restrict__ W10,const float* __restrict__ W20,const float* __restrict__ Wa0,const float* __restrict__ Wb0,
    const float* __restrict__ b10,const float* __restrict__ b20,const float* __restrict__ ba0,const float* __restrict__ bb0,
    const int* __restrict__ M0,
    const float* __restrict__ W11,const float* __restrict__ W21,const float* __restrict__ Wa1,const float* __restrict__ Wb1,
    const float* __restrict__ b11,const float* __restrict__ b21,const float* __restrict__ ba1,const float* __restrict__ bb1,
    const int* __restrict__ M1,
    const float* __restrict__ W12,const float* __restrict__ W22,const float* __restrict__ Wa2,const float* __restrict__ Wb2,
    const float* __restrict__ b12,const float* __restrict__ b22,const float* __restrict__ ba2,const float* __restrict__ bb2,
    const int* __restrict__ M2,
    const float* __restrict__ Wo, f16* __restrict__ ws)
{
  int idx=blockIdx.x*256+threadIdx.x;
  if(idx>=16704) return;
  int tile=idx>>6, lane=idx&63, ml=lane&15, grp=lane>>4;
  int lay,nb,m,kt,c,h;
  const float *w1,*w2,*wa,*wb,*c1,*c2,*ca,*cb; const int* M;
  if(tile<96){ lay=0; int u=tile; kt=u&3; int q=u>>2; m=q%3; nb=q/3; c=117; h=116;
    w1=W10;w2=W20;wa=Wa0;wb=Wb0;M=M0;c1=b10;c2=b20;ca=ba0;cb=bb0; }
  else if(tile<201){ lay=1; int u=tile-96; kt=u%7; int q=u/7; m=q%3; nb=q/3; c=192; h=76;
    w1=W11;w2=W21;wa=Wa1;wb=Wb1;M=M1;c1=b11;c2=b21;ca=ba1;cb=bb1; }
  else { lay=2; int u=tile-201; kt=u%5; int q=u/5; m=q%3; nb=q/3; c=140; h=64;
    w1=W12;w2=W22;wa=Wa2;wb=Wb2;M=M2;c1=b12;c2=b22;ca=ba2;cb=bb2; }
  int n=nb*16+ml;
  float sc=(m<2)?S12f:SABf;
  int k0=kt*32+grp*8;
  F16x8 fr;
  #pragma unroll
  for(int j=0;j<8;++j){
    int k=k0+j; float v=0.f; int col=-1;
    if(lay==0){       if(k<116) col=1+k; else if(k==124) col=0; else if(k==125) col=-2; }
    else if(lay==1){  if(k<116) col=k; else if(k>=128 && k<204) col=116+(k-128); else if(k==125) col=-2; }
    else {            if(k<76) col=k; else if(k>=96 && k<160) col=76+(k-96); else if(k==88) col=-2; }
    if(n<h){
      if(col>=0){
        if(m==0){ v=w1[n*c+col]*(float)M[n*c+col]; }
        else if(m==1){ v=w2[n*c+col]*(float)M[n*c+col]; }
        else { v=wa[n*c+col]+wb[n*c+col]; }        // unmasked per reference
      } else if(col==-2){
        v=(m==0)?c1[n]:(m==1)?c2[n]:(ca[n]+cb[n]);
      }
    }
    fr[j]=(f16)(v*sc);
  }
  ((F16x8*)ws)[idx]=fr;
}

// ---------------- main: 32 WGs x 1024 thr; systolic; gate-major triplets, packed b64 state writes ----------------
// wave->role (SIMD=w&3 balanced to ~65 MFMA):
//  w0: MERGE (L0 nb7 + L2 nb3)         [27]
//  w1,w5,w2,w3,w7: L1 nb 0,1,2,3,4     [21]
//  w4,w6,w10: L2 nb 0,1,2              [15]  (w6 also dt-writer)
//  w8,w12,w9,w13,w14,w11,w15: L0 nb 0..6 [12] (w9,w14 also stream h2->d_out)
__global__ __launch_bounds__(1024,4) void cfc_main(
    const float* __restrict__ dtp, const float* __restrict__ hxp,
    const f16* __restrict__ ws, float* __restrict__ outp)
{
  const int tid=threadIdx.x, lane=tid&63, w=tid>>6;
  const int b_l=lane&15, g_l=lane>>4;
  const int gb0=blockIdx.x*16;

  __shared__ alignas(16) f16 H0[2][2048];   // h0 | dt@124 | one@125, Kpad=128
  __shared__ alignas(16) f16 H1[2][1536];   // h1 | one@88, Kpad=96
  __shared__ alignas(16) f16 H2[2][1024];   // h2, K=64 (streaming source)
  __shared__ f16 DTS[16448];                // [t][b] stride 16, rows 1024..1027 zero

  const F16x8* wsf=(const F16x8*)ws;
  F32x4 ZED; ZED[0]=0.f; ZED[1]=0.f; ZED[2]=0.f; ZED[3]=0.f;

  // ---- init ----
  for(int i=tid;i<4096;i+=1024) ((f16*)H0)[i]=(f16)0.f;
  for(int i=tid;i<3072;i+=1024) ((f16*)H1)[i]=(f16)0.f;
  for(int i=tid;i<2048;i+=1024) ((f16*)H2)[i]=(f16)0.f;
  for(int i=tid;i<16448;i+=1024){
    int t=i>>4, b=i&15;
    DTS[i]=(t<1024)?(f16)dtp[(size_t)(gb0+b)*1024+t]:(f16)0.f;
  }
  __syncthreads();
  for(int i=tid;i<4096;i+=1024){ int b=i>>8,u=i&255; f16 v=(f16)hxp[(size_t)(gb0+b)*256+u];
    if(u<116){ H0[0][fidx(u,b)]=v; H0[1][fidx(u,b)]=v; }
    else if(u<192){ int n=u-116; H1[0][fidx(n,b)]=v; H1[1][fidx(n,b)]=v; }
    else { int n=u-192; H2[0][fidx(n,b)]=v; H2[1][fidx(n,b)]=v; }
  }
  if(tid<16){
    H0[1][fidx(124,tid)]=DTS[tid];               // dt(0) for tick 0
    H0[0][fidx(125,tid)]=(f16)1.f; H0[1][fidx(125,tid)]=(f16)1.f;
    H1[0][fidx(88,tid)]=(f16)1.f;  H1[1][fidx(88,tid)]=(f16)1.f;
  }
  __syncthreads();

  // role decode (wave-uniform)
  int type, nb=0;
  if(w==0){ type=0; }
  else if(w==1){type=1;nb=0;} else if(w==5){type=1;nb=1;} else if(w==2){type=1;nb=2;}
  else if(w==3){type=1;nb=3;} else if(w==7){type=1;nb=4;}
  else if(w==4){type=3;nb=0;} else if(w==6){type=3;nb=1;} else if(w==10){type=3;nb=2;}
  else { type=2; nb=(w==8)?0:(w==12)?1:(w==9)?2:(w==13)?3:(w==14)?4:(w==11)?5:6; }

  if(type==0){
    // ================= MERGE: L0 nb7 (write n=112..115, g_l==0) + L2 nb3 =================
    F16x8 wm0[3][4], wm2[3][5];
    #pragma unroll
    for(int m=0;m<3;++m){
      #pragma unroll
      for(int kt=0;kt<4;++kt) wm0[m][kt]=wsf[((7*3+m)*4+kt)*64+lane];
      #pragma unroll
      for(int kt=0;kt<5;++kt) wm2[m][kt]=wsf[(201+(3*3+m)*5+kt)*64+lane];
    }
    const int wk0=fidx(112+g_l*4,b_l);   // valid only g_l==0
    const int wk2=fidx(48+g_l*4,b_l);
#define MG_TICK(I_,P_) do{ \
      if((I_)<=1023){ \
        F16x8 Af0=((const F16x8*)H0[(P_)^1])[0*64+lane]; \
        F16x8 Af1=((const F16x8*)H0[(P_)^1])[1*64+lane]; \
        F16x8 Af2=((const F16x8*)H0[(P_)^1])[2*64+lane]; \
        F16x8 Af3=((const F16x8*)H0[(P_)^1])[3*64+lane]; \
        F32x4 a0=MFMA16(wm0[0][0],Af0,ZED), a1=MFMA16(wm0[1][0],Af0,ZED), a2=MFMA16(wm0[2][0],Af0,ZED); \
        a0=MFMA16(wm0[0][1],Af1,a0); a1=MFMA16(wm0[1][1],Af1,a1); a2=MFMA16(wm0[2][1],Af1,a2); \
        a0=MFMA16(wm0[0][2],Af2,a0); a1=MFMA16(wm0[1][2],Af2,a1); a2=MFMA16(wm0[2][2],Af2,a2); \
        a0=MFMA16(wm0[0][3],Af3,a0); a1=MFMA16(wm0[1][3],Af3,a1); a2=MFMA16(wm0[2][3],Af3,a2); \
        if(g_l==0){ \
          F16x4 v; v[0]=cfc_act3(a0[0],a1[0],a2[0]); v[1]=cfc_act3(a0[1],a1[1],a2[1]); \
          v[2]=cfc_act3(a0[2],a1[2],a2[2]); v[3]=cfc_act3(a0[3],a1[3],a2[3]); \
          *(F16x4*)&H0[P_][wk0]=v; } \
      } \
      if((I_)>=2 && (I_)<=1025){ \
        F16x8 Cf0=((const F16x8*)H1[(P_)^1])[0*64+lane]; \
        F16x8 Cf1=((const F16x8*)H1[(P_)^1])[1*64+lane]; \
        F16x8 Cf2=((const F16x8*)H1[(P_)^1])[2*64+lane]; \
        F16x8 Cf3=((const F16x8*)H2[(P_)^1])[0*64+lane]; \
        F16x8 Cf4=((const F16x8*)H2[(P_)^1])[1*64+lane]; \
        F32x4 c0=MFMA16(wm2[0][0],Cf0,ZED), c1=MFMA16(wm2[1][0],Cf0,ZED), c2=MFMA16(wm2[2][0],Cf0,ZED); \
        c0=MFMA16(wm2[0][1],Cf1,c0); c1=MFMA16(wm2[1][1],Cf1,c1); c2=MFMA16(wm2[2][1],Cf1,c2); \
        c0=MFMA16(wm2[0][2],Cf2,c0); c1=MFMA16(wm2[1][2],Cf2,c1); c2=MFMA16(wm2[2][2],Cf2,c2); \
        c0=MFMA16(wm2[0][3],Cf3,c0); c1=MFMA16(wm2[1][3],Cf3,c1); c2=MFMA16(wm2[2][3],Cf3,c2); \
        c0=MFMA16(wm2[0][4],Cf4,c0); c1=MFMA16(wm2[1][4],Cf4,c1); c2=MFMA16(wm2[2][4],Cf4,c2); \
        F16x4 v; v[0]=cfc_act3(c0[0],c1[0],c2[0]); v[1]=cfc_act3(c0[1],c1[1],c2[1]); \
        v[2]=cfc_act3(c0[2],c1[2],c2[2]); v[3]=cfc_act3(c0[3],c1[3],c2[3]); \
        *(F16x4*)&H2[P_][wk2]=v; \
      } }while(0)
    for(int I2=0;I2<1028;I2+=2){
      MG_TICK(I2,0);   tick_barrier();
      MG_TICK(I2+1,1); tick_barrier();
    }
#undef MG_TICK
  } else if(type==1){
    // ================= L1 triplet =================
    F16x8 wf[3][7];
    #pragma unroll
    for(int m=0;m<3;++m)
      #pragma unroll
      for(int kt=0;kt<7;++kt) wf[m][kt]=wsf[(96+(nb*3+m)*7+kt)*64+lane];
    const int wk=fidx(nb*16+g_l*4,b_l);
    const bool wr_ok=(nb<4)||(g_l<3);    // nb4: n>=76 invalid
#define L1_TICK(I_,P_) do{ \
      if((I_)>=1 && (I_)<=1024){ \
        F16x8 Af0=((const F16x8*)H0[(P_)^1])[0*64+lane]; \
        F16x8 Af1=((const F16x8*)H0[(P_)^1])[1*64+lane]; \
        F16x8 Af2=((const F16x8*)H0[(P_)^1])[2*64+lane]; \
        F16x8 Af3=((const F16x8*)H0[(P_)^1])[3*64+lane]; \
        F16x8 Hf0=((const F16x8*)H1[(P_)^1])[0*64+lane]; \
        F16x8 Hf1=((const F16x8*)H1[(P_)^1])[1*64+lane]; \
        F16x8 Hf2=((const F16x8*)H1[(P_)^1])[2*64+lane]; \
        F32x4 a0=MFMA16(wf[0][0],Af0,ZED), a1=MFMA16(wf[1][0],Af0,ZED), a2=MFMA16(wf[2][0],Af0,ZED); \
        a0=MFMA16(wf[0][1],Af1,a0); a1=MFMA16(wf[1][1],Af1,a1); a2=MFMA16(wf[2][1],Af1,a2); \
        a0=MFMA16(wf[0][2],Af2,a0); a1=MFMA16(wf[1][2],Af2,a1); a2=MFMA16(wf[2][2],Af2,a2); \
        a0=MFMA16(wf[0][3],Af3,a0); a1=MFMA16(wf[1][3],Af3,a1); a2=MFMA16(wf[2][3],Af3,a2); \
        a0=MFMA16(wf[0][4],Hf0,a0); a1=MFMA16(wf[1][4],Hf0,a1); a2=MFMA16(wf[2][4],Hf0,a2); \
        a0=MFMA16(wf[0][5],Hf1,a0); a1=MFMA16(wf[1][5],Hf1,a1); a2=MFMA16(wf[2][5],Hf1,a2); \
        a0=MFMA16(wf[0][6],Hf2,a0); a1=MFMA16(wf[1][6],Hf2,a1); a2=MFMA16(wf[2][6],Hf2,a2); \
        F16x4 v; v[0]=cfc_act3(a0[0],a1[0],a2[0]); v[1]=cfc_act3(a0[1],a1[1],a2[1]); \
        v[2]=cfc_act3(a0[2],a1[2],a2[2]); v[3]=cfc_act3(a0[3],a1[3],a2[3]); \
        if(wr_ok) *(F16x4*)&H1[P_][wk]=v; \
      } }while(0)
    for(int I2=0;I2<1028;I2+=2){
      L1_TICK(I2,0);   tick_barrier();
      L1_TICK(I2+1,1); tick_barrier();
    }
#undef L1_TICK
  } else if(type==2){
    // ================= L0 triplet (+streaming on w9,w14) =================
    F16x8 wf[3][4];
    #pragma unroll
    for(int m=0;m<3;++m)
      #pragma unroll
      for(int kt=0;kt<4;++kt) wf[m][kt]=wsf[((nb*3+m)*4+kt)*64+lane];
    const int wk=fidx(nb*16+g_l*4,b_l);   // nb<=6 -> n<=111 all valid
    const bool dost=(w==9)||(w==14);
    const int q=lane&7, bb=(lane>>3)+8*((w==9)?0:1);
    char* outPtr=(char*)outp + ((size_t)(gb0+bb)*1024)*128 + q*16;
#define L0_TICK(I_,P_) do{ \
      if((I_)<=1023){ \
        F16x8 Af0=((const F16x8*)H0[(P_)^1])[0*64+lane]; \
        F16x8 Af1=((const F16x8*)H0[(P_)^1])[1*64+lane]; \
        F16x8 Af2=((const F16x8*)H0[(P_)^1])[2*64+lane]; \
        F16x8 Af3=((const F16x8*)H0[(P_)^1])[3*64+lane]; \
        F32x4 a0=MFMA16(wf[0][0],Af0,ZED), a1=MFMA16(wf[1][0],Af0,ZED), a2=MFMA16(wf[2][0],Af0,ZED); \
        a0=MFMA16(wf[0][1],Af1,a0); a1=MFMA16(wf[1][1],Af1,a1); a2=MFMA16(wf[2][1],Af1,a2); \
        a0=MFMA16(wf[0][2],Af2,a0); a1=MFMA16(wf[1][2],Af2,a1); a2=MFMA16(wf[2][2],Af2,a2); \
        a0=MFMA16(wf[0][3],Af3,a0); a1=MFMA16(wf[1][3],Af3,a1); a2=MFMA16(wf[2][3],Af3,a2); \
        F16x4 v; v[0]=cfc_act3(a0[0],a1[0],a2[0]); v[1]=cfc_act3(a0[1],a1[1],a2[1]); \
        v[2]=cfc_act3(a0[2],a1[2],a2[2]); v[3]=cfc_act3(a0[3],a1[3],a2[3]); \
        *(F16x4*)&H0[P_][wk]=v; \
      } \
      if(dost && (I_)>=3 && (I_)<=1026){ \
        F16x8 sv=((const F16x8*)H2[(P_)^1])[q*16+bb]; \
        *(F16x8*)outPtr=sv; outPtr+=128; \
      } }while(0)
    for(int I2=0;I2<1028;I2+=2){
      L0_TICK(I2,0);   tick_barrier();
      L0_TICK(I2+1,1); tick_barrier();
    }
#undef L0_TICK
  } else {
    // ================= L2 triplet (+dt writer on w6) =================
    F16x8 wf[3][5];
    #pragma unroll
    for(int m=0;m<3;++m)
      #pragma unroll
      for(int kt=0;kt<5;++kt) wf[m][kt]=wsf[(201+(nb*3+m)*5+kt)*64+lane];
    const int wk=fidx(nb*16+g_l*4,b_l);   // nb<=2 -> n<=47 valid
    const bool dodt=(w==6);
#define L2_TICK(I_,P_) do{ \
      if(dodt && lane<16 && (I_)<=1022) H0[P_][fidx(124,lane)]=DTS[((I_)+1)*16+lane]; \
      if((I_)>=2 && (I_)<=1025){ \
        F16x8 Cf0=((const F16x8*)H1[(P_)^1])[0*64+lane]; \
        F16x8 Cf1=((const F16x8*)H1[(P_)^1])[1*64+lane]; \
        F16x8 Cf2=((const F16x8*)H1[(P_)^1])[2*64+lane]; \
        F16x8 Cf3=((const F16x8*)H2[(P_)^1])[0*64+lane]; \
        F16x8 Cf4=((const F16x8*)H2[(P_)^1])[1*64+lane]; \
        F32x4 a0=MFMA16(wf[0][0],Cf0,ZED), a1=MFMA16(wf[1][0],Cf0,ZED), a2=MFMA16(wf[2][0],Cf0,ZED); \
        a0=MFMA16(wf[0][1],Cf1,a0); a1=MFMA16(wf[1][1],Cf1,a1); a2=MFMA16(wf[2][1],Cf1,a2); \
        a0=MFMA16(wf[0][2],Cf2,a0); a1=MFMA16(wf[1][2],Cf2,a1); a2=MFMA16(wf[2][2],Cf2,a2); \
        a0=MFMA16(wf[0][3],Cf3,a0); a1=MFMA16(wf[1][3],Cf3,a1); a2=MFMA16(wf[2][3],Cf3,a2); \
        a0=MFMA16(wf[0][4],Cf4,a0); a1=MFMA16(wf[1][4],Cf4,a1); a2=MFMA16(wf[2][4],Cf4,a2); \
        F16x4 v; v[0]=cfc_act3(a0[0],a1[0],a2[0]); v[1]=cfc_act3(a0[1],a1[1],a2[1]); \
        v[2]=cfc_act3(a0[2],a1[2],a2[2]); v[3]=cfc_act3(a0[3],a1[3],a2[3]); \
        *(F16x4*)&H2[P_][wk]=v; \
      } }while(0)
    for(int I2=0;I2<1028;I2+=2){
      L2_TICK(I2,0);   tick_barrier();
      L2_TICK(I2+1,1); tick_barrier();
    }
#undef L2_TICK
  }
}

// ---------------- post: in-place d_out transform  h2(64 f16) -> y(32 f32) per (b,t) slot ----------------
__global__ __launch_bounds__(256) void cfc_ro(
    const float* __restrict__ Wo, const float* __restrict__ bo, float* __restrict__ outp)
{
  __shared__ h2v wT[1024];   // [kp][o]
  __shared__ float bs[32];
  int tid=threadIdx.x;
  for(int i=tid;i<1024;i+=256){ int kp=i>>5,o=i&31;
    h2v v; v[0]=(f16)Wo[o*64+2*kp]; v[1]=(f16)Wo[o*64+2*kp+1]; wT[i]=v; }
  if(tid<32) bs[tid]=bo[tid];
  __syncthreads();
  size_t s=(size_t)blockIdx.x*256+tid;      // 0..524287 = b*1024+t
  float* slot=outp+s*32;
  h2v x[32];
  #pragma unroll
  for(int r=0;r<8;++r) ((F16x8*)x)[r]=((const F16x8*)slot)[r];
  float y[32];
  #pragma unroll
  for(int o=0;o<32;++o){
    float acc=bs[o];
    #pragma unroll
    for(int kp=0;kp<32;++kp) acc=__builtin_amdgcn_fdot2(x[kp],wT[kp*32+o],acc,false);
    y[o]=acc;
  }
  #pragma unroll
  for(int r=0;r<8;++r) ((float4*)slot)[r]=((const float4*)y)[r];
}

extern "C" void kernel_launch(void* const* d_in, const int* in_sizes, int n_in,
                              void* d_out, int out_size, void* d_ws, size_t ws_size,
                              hipStream_t stream)
{
  (void)in_sizes; (void)n_in; (void)out_size; (void)ws_size;
  f16* ws=(f16*)d_ws;
  cfc_prep<<<66,256,0,stream>>>(
    (const float*)d_in[2],(const float*)d_in[3],(const float*)d_in[4],(const float*)d_in[5],
    (const float*)d_in[6],(const float*)d_in[7],(const float*)d_in[8],(const float*)d_in[9],
    (const int*)d_in[10],
    (const float*)d_in[11],(const float*)d_in[12],(const float*)d_in[13],(const float*)d_in[14],
    (const float*)d_in[15],(const float*)d_in[16],(const float*)d_in[17],(const float*)d_in[18],
    (const int*)d_in[19],
    (const float*)d_in[20],(const float*)d_in[21],(const float*)d_in[22],(const float*)d_in[23],
    (const float*)d_in[24],(const float*)d_in[25],(const float*)d_in[26],(const float*)d_in[27],
    (const int*)d_in[28],
    (const float*)d_in[29], ws);
  cfc_main<<<32,1024,0,stream>>>(
    (const float*)d_in[0],(const float*)d_in[1], ws, (float*)d_out);
  cfc_ro<<<2048,256,0,stream>>>(
    (const float*)d_in[29],(const float*)d_in[30],(float*)d_out);
}

// Round 18
// 1036.725 us; speedup vs baseline: 1.1011x; 1.0032x over previous
//
#include <hip/hip_runtime.h>
#include <stdint.h>

typedef _Float16 f16;
typedef _Float16 h2v __attribute__((ext_vector_type(2)));
typedef _Float16 F16x4 __attribute__((ext_vector_type(4)));
typedef _Float16 F16x8 __attribute__((ext_vector_type(8)));
typedef float F32x4 __attribute__((ext_vector_type(4)));

#define MFMA16(a,b,c) __builtin_amdgcn_mfma_f32_16x16x32_f16((a),(b),(c),0,0,0)
#define S12f 2.8853900817779268f    // 2*log2(e): folded into W1,W2,b1,b2
#define SABf (-1.4426950408889634f) // -log2(e): folded into (Wa+Wb),(ba+bb)
#define PRIO1() __builtin_amdgcn_s_setprio(1)
#define PRIO0() __builtin_amdgcn_s_setprio(0)

// builtin only (inline-asm v_exp_f32 lacks TRANS hazard handling; r6/r7 failures)
static __device__ __forceinline__ float exp2f_b(float x){ return __builtin_amdgcn_exp2f(x); }

// 3-gate act: p1,p2 prescaled by 2log2e; ps = -log2e*(x@(Wa+Wb)+ba+bb)
static __device__ __forceinline__ f16 cfc_act3(float p1,float p2,float ps){
  float E1=exp2f_b(p1), E2=exp2f_b(p2), es=exp2f_b(ps);
  float t1=E1+1.f, u=(E2+1.f)*(1.f+es);
  float num=u-(E2-E1);
  float r=__builtin_amdgcn_rcpf(t1*u);
  return (f16)(1.f-2.f*num*r);
}
// frag-interleaved layout: value (k,b) at (k>>3)*128 + b*8 + (k&7)
static __device__ __forceinline__ int fidx(int k,int b){ return ((k>>3)<<7)+(b<<3)+(k&7); }

// tick barrier WITHOUT vmcnt(0) drain
static __device__ __forceinline__ void tick_barrier(){
  asm volatile("s_waitcnt lgkmcnt(0)" ::: "memory");
  __builtin_amdgcn_s_barrier();
}

// ---------------- prep (byte-identical to r17's validated version) ----------------
__global__ __launch_bounds__(256) void cfc_prep(
    const float* __restrict__ W10,const float* __restrict__ W20,const float* __restrict__ Wa0,const float* __restrict__ Wb0,
    const float* __restrict__ b10,const float* __restrict__ b20,const float* __restrict__ ba0,const float* __restrict__ bb0,
    const int* __restrict__ M0,
    const float* __restrict__ W11,const float* __restrict__ W21,const float* __restrict__ Wa1,const float* __restrict__ Wb1,
    const float* __restrict__ b11,const float* __restrict__ b21,const float* __restrict__ ba1,const float* __restrict__ bb1,
    const int* __restrict__ M1,
    const float* __restrict__ W12,const float* __restrict__ W22,const float* __restrict__ Wa2,const float* __restrict__ Wb2,
    const float* __restrict__ b12,const float* __restrict__ b22,const float* __restrict__ ba2,const float* __restrict__ bb2,
    const int* __restrict__ M2,
    const float* __restrict__ Wo, f16* __restrict__ ws)
{
  int idx=blockIdx.x*256+threadIdx.x;
  if(idx>=16704) return;
  int tile=idx>>6, lane=idx&63, ml=lane&15, grp=lane>>4;
  int lay,nb,m,kt,c,h;
  const float *w1,*w2,*wa,*wb,*c1,*c2,*ca,*cb; const int* M;
  if(tile<96){ lay=0; int u=tile; kt=u&3; int q=u>>2; m=q%3; nb=q/3; c=117; h=116;
    w1=W10;w2=W20;wa=Wa0;wb=Wb0;M=M0;c1=b10;c2=b20;ca=ba0;cb=bb0; }
  else if(tile<201){ lay=1; int u=tile-96; kt=u%7; int q=u/7; m=q%3; nb=q/3; c=192; h=76;
    w1=W11;w2=W21;wa=Wa1;wb=Wb1;M=M1;c1=b11;c2=b21;ca=ba1;cb=bb1; }
  else { lay=2; int u=tile-201; kt=u%5; int q=u/5; m=q%3; nb=q/3; c=140; h=64;
    w1=W12;w2=W22;wa=Wa2;wb=Wb2;M=M2;c1=b12;c2=b22;ca=ba2;cb=bb2; }
  int n=nb*16+ml;
  float sc=(m<2)?S12f:SABf;
  int k0=kt*32+grp*8;
  F16x8 fr;
  #pragma unroll
  for(int j=0;j<8;++j){
    int k=k0+j; float v=0.f; int col=-1;
    if(lay==0){       if(k<116) col=1+k; else if(k==124) col=0; else if(k==125) col=-2; }
    else if(lay==1){  if(k<116) col=k; else if(k>=128 && k<204) col=116+(k-128); else if(k==125) col=-2; }
    else {            if(k<76) col=k; else if(k>=96 && k<160) col=76+(k-96); else if(k==88) col=-2; }
    if(n<h){
      if(col>=0){
        if(m==0){ v=w1[n*c+col]*(float)M[n*c+col]; }
        else if(m==1){ v=w2[n*c+col]*(float)M[n*c+col]; }
        else { v=wa[n*c+col]+wb[n*c+col]; }        // unmasked per reference
      } else if(col==-2){
        v=(m==0)?c1[n]:(m==1)?c2[n]:(ca[n]+cb[n]);
      }
    }
    fr[j]=(f16)(v*sc);
  }
  ((F16x8*)ws)[idx]=fr;
}

// ---------------- main: r17 host + T5 setprio around MFMA clusters (role-split regime) ----------------
__global__ __launch_bounds__(1024,4) void cfc_main(
    const float* __restrict__ dtp, const float* __restrict__ hxp,
    const f16* __restrict__ ws, float* __restrict__ outp)
{
  const int tid=threadIdx.x, lane=tid&63, w=tid>>6;
  const int b_l=lane&15, g_l=lane>>4;
  const int gb0=blockIdx.x*16;

  __shared__ alignas(16) f16 H0[2][2048];   // h0 | dt@124 | one@125, Kpad=128
  __shared__ alignas(16) f16 H1[2][1536];   // h1 | one@88, Kpad=96
  __shared__ alignas(16) f16 H2[2][1024];   // h2, K=64 (streaming source)
  __shared__ f16 DTS[16448];                // [t][b] stride 16, rows 1024..1027 zero

  const F16x8* wsf=(const F16x8*)ws;
  F32x4 ZED; ZED[0]=0.f; ZED[1]=0.f; ZED[2]=0.f; ZED[3]=0.f;

  // ---- init ----
  for(int i=tid;i<4096;i+=1024) ((f16*)H0)[i]=(f16)0.f;
  for(int i=tid;i<3072;i+=1024) ((f16*)H1)[i]=(f16)0.f;
  for(int i=tid;i<2048;i+=1024) ((f16*)H2)[i]=(f16)0.f;
  for(int i=tid;i<16448;i+=1024){
    int t=i>>4, b=i&15;
    DTS[i]=(t<1024)?(f16)dtp[(size_t)(gb0+b)*1024+t]:(f16)0.f;
  }
  __syncthreads();
  for(int i=tid;i<4096;i+=1024){ int b=i>>8,u=i&255; f16 v=(f16)hxp[(size_t)(gb0+b)*256+u];
    if(u<116){ H0[0][fidx(u,b)]=v; H0[1][fidx(u,b)]=v; }
    else if(u<192){ int n=u-116; H1[0][fidx(n,b)]=v; H1[1][fidx(n,b)]=v; }
    else { int n=u-192; H2[0][fidx(n,b)]=v; H2[1][fidx(n,b)]=v; }
  }
  if(tid<16){
    H0[1][fidx(124,tid)]=DTS[tid];               // dt(0) for tick 0
    H0[0][fidx(125,tid)]=(f16)1.f; H0[1][fidx(125,tid)]=(f16)1.f;
    H1[0][fidx(88,tid)]=(f16)1.f;  H1[1][fidx(88,tid)]=(f16)1.f;
  }
  __syncthreads();

  // role decode (wave-uniform)
  int type, nb=0;
  if(w==0){ type=0; }
  else if(w==1){type=1;nb=0;} else if(w==5){type=1;nb=1;} else if(w==2){type=1;nb=2;}
  else if(w==3){type=1;nb=3;} else if(w==7){type=1;nb=4;}
  else if(w==4){type=3;nb=0;} else if(w==6){type=3;nb=1;} else if(w==10){type=3;nb=2;}
  else { type=2; nb=(w==8)?0:(w==12)?1:(w==9)?2:(w==13)?3:(w==14)?4:(w==11)?5:6; }

  if(type==0){
    // ================= MERGE: L0 nb7 (write n=112..115, g_l==0) + L2 nb3 =================
    F16x8 wm0[3][4], wm2[3][5];
    #pragma unroll
    for(int m=0;m<3;++m){
      #pragma unroll
      for(int kt=0;kt<4;++kt) wm0[m][kt]=wsf[((7*3+m)*4+kt)*64+lane];
      #pragma unroll
      for(int kt=0;kt<5;++kt) wm2[m][kt]=wsf[(201+(3*3+m)*5+kt)*64+lane];
    }
    const int wk0=fidx(112+g_l*4,b_l);   // valid only g_l==0
    const int wk2=fidx(48+g_l*4,b_l);
#define MG_TICK(I_,P_) do{ \
      if((I_)<=1023){ \
        F16x8 Af0=((const F16x8*)H0[(P_)^1])[0*64+lane]; \
        F16x8 Af1=((const F16x8*)H0[(P_)^1])[1*64+lane]; \
        F16x8 Af2=((const F16x8*)H0[(P_)^1])[2*64+lane]; \
        F16x8 Af3=((const F16x8*)H0[(P_)^1])[3*64+lane]; \
        PRIO1(); \
        F32x4 a0=MFMA16(wm0[0][0],Af0,ZED), a1=MFMA16(wm0[1][0],Af0,ZED), a2=MFMA16(wm0[2][0],Af0,ZED); \
        a0=MFMA16(wm0[0][1],Af1,a0); a1=MFMA16(wm0[1][1],Af1,a1); a2=MFMA16(wm0[2][1],Af1,a2); \
        a0=MFMA16(wm0[0][2],Af2,a0); a1=MFMA16(wm0[1][2],Af2,a1); a2=MFMA16(wm0[2][2],Af2,a2); \
        a0=MFMA16(wm0[0][3],Af3,a0); a1=MFMA16(wm0[1][3],Af3,a1); a2=MFMA16(wm0[2][3],Af3,a2); \
        PRIO0(); \
        if(g_l==0){ \
          F16x4 v; v[0]=cfc_act3(a0[0],a1[0],a2[0]); v[1]=cfc_act3(a0[1],a1[1],a2[1]); \
          v[2]=cfc_act3(a0[2],a1[2],a2[2]); v[3]=cfc_act3(a0[3],a1[3],a2[3]); \
          *(F16x4*)&H0[P_][wk0]=v; } \
      } \
      if((I_)>=2 && (I_)<=1025){ \
        F16x8 Cf0=((const F16x8*)H1[(P_)^1])[0*64+lane]; \
        F16x8 Cf1=((const F16x8*)H1[(P_)^1])[1*64+lane]; \
        F16x8 Cf2=((const F16x8*)H1[(P_)^1])[2*64+lane]; \
        F16x8 Cf3=((const F16x8*)H2[(P_)^1])[0*64+lane]; \
        F16x8 Cf4=((const F16x8*)H2[(P_)^1])[1*64+lane]; \
        PRIO1(); \
        F32x4 c0=MFMA16(wm2[0][0],Cf0,ZED), c1=MFMA16(wm2[1][0],Cf0,ZED), c2=MFMA16(wm2[2][0],Cf0,ZED); \
        c0=MFMA16(wm2[0][1],Cf1,c0); c1=MFMA16(wm2[1][1],Cf1,c1); c2=MFMA16(wm2[2][1],Cf1,c2); \
        c0=MFMA16(wm2[0][2],Cf2,c0); c1=MFMA16(wm2[1][2],Cf2,c1); c2=MFMA16(wm2[2][2],Cf2,c2); \
        c0=MFMA16(wm2[0][3],Cf3,c0); c1=MFMA16(wm2[1][3],Cf3,c1); c2=MFMA16(wm2[2][3],Cf3,c2); \
        c0=MFMA16(wm2[0][4],Cf4,c0); c1=MFMA16(wm2[1][4],Cf4,c1); c2=MFMA16(wm2[2][4],Cf4,c2); \
        PRIO0(); \
        F16x4 v; v[0]=cfc_act3(c0[0],c1[0],c2[0]); v[1]=cfc_act3(c0[1],c1[1],c2[1]); \
        v[2]=cfc_act3(c0[2],c1[2],c2[2]); v[3]=cfc_act3(c0[3],c1[3],c2[3]); \
        *(F16x4*)&H2[P_][wk2]=v; \
      } }while(0)
    for(int I2=0;I2<1028;I2+=2){
      MG_TICK(I2,0);   tick_barrier();
      MG_TICK(I2+1,1); tick_barrier();
    }
#undef MG_TICK
  } else if(type==1){
    // ================= L1 triplet =================
    F16x8 wf[3][7];
    #pragma unroll
    for(int m=0;m<3;++m)
      #pragma unroll
      for(int kt=0;kt<7;++kt) wf[m][kt]=wsf[(96+(nb*3+m)*7+kt)*64+lane];
    const int wk=fidx(nb*16+g_l*4,b_l);
    const bool wr_ok=(nb<4)||(g_l<3);    // nb4: n>=76 invalid
#define L1_TICK(I_,P_) do{ \
      if((I_)>=1 && (I_)<=1024){ \
        F16x8 Af0=((const F16x8*)H0[(P_)^1])[0*64+lane]; \
        F16x8 Af1=((const F16x8*)H0[(P_)^1])[1*64+lane]; \
        F16x8 Af2=((const F16x8*)H0[(P_)^1])[2*64+lane]; \
        F16x8 Af3=((const F16x8*)H0[(P_)^1])[3*64+lane]; \
        F16x8 Hf0=((const F16x8*)H1[(P_)^1])[0*64+lane]; \
        F16x8 Hf1=((const F16x8*)H1[(P_)^1])[1*64+lane]; \
        F16x8 Hf2=((const F16x8*)H1[(P_)^1])[2*64+lane]; \
        PRIO1(); \
        F32x4 a0=MFMA16(wf[0][0],Af0,ZED), a1=MFMA16(wf[1][0],Af0,ZED), a2=MFMA16(wf[2][0],Af0,ZED); \
        a0=MFMA16(wf[0][1],Af1,a0); a1=MFMA16(wf[1][1],Af1,a1); a2=MFMA16(wf[2][1],Af1,a2); \
        a0=MFMA16(wf[0][2],Af2,a0); a1=MFMA16(wf[1][2],Af2,a1); a2=MFMA16(wf[2][2],Af2,a2); \
        a0=MFMA16(wf[0][3],Af3,a0); a1=MFMA16(wf[1][3],Af3,a1); a2=MFMA16(wf[2][3],Af3,a2); \
        a0=MFMA16(wf[0][4],Hf0,a0); a1=MFMA16(wf[1][4],Hf0,a1); a2=MFMA16(wf[2][4],Hf0,a2); \
        a0=MFMA16(wf[0][5],Hf1,a0); a1=MFMA16(wf[1][5],Hf1,a1); a2=MFMA16(wf[2][5],Hf1,a2); \
        a0=MFMA16(wf[0][6],Hf2,a0); a1=MFMA16(wf[1][6],Hf2,a1); a2=MFMA16(wf[2][6],Hf2,a2); \
        PRIO0(); \
        F16x4 v; v[0]=cfc_act3(a0[0],a1[0],a2[0]); v[1]=cfc_act3(a0[1],a1[1],a2[1]); \
        v[2]=cfc_act3(a0[2],a1[2],a2[2]); v[3]=cfc_act3(a0[3],a1[3],a2[3]); \
        if(wr_ok) *(F16x4*)&H1[P_][wk]=v; \
      } }while(0)
    for(int I2=0;I2<1028;I2+=2){
      L1_TICK(I2,0);   tick_barrier();
      L1_TICK(I2+1,1); tick_barrier();
    }
#undef L1_TICK
  } else if(type==2){
    // ================= L0 triplet (+streaming on w9,w14) =================
    F16x8 wf[3][4];
    #pragma unroll
    for(int m=0;m<3;++m)
      #pragma unroll
      for(int kt=0;kt<4;++kt) wf[m][kt]=wsf[((nb*3+m)*4+kt)*64+lane];
    const int wk=fidx(nb*16+g_l*4,b_l);   // nb<=6 -> n<=111 all valid
    const bool dost=(w==9)||(w==14);
    const int q=lane&7, bb=(lane>>3)+8*((w==9)?0:1);
    char* outPtr=(char*)outp + ((size_t)(gb0+bb)*1024)*128 + q*16;
#define L0_TICK(I_,P_) do{ \
      if((I_)<=1023){ \
        F16x8 Af0=((const F16x8*)H0[(P_)^1])[0*64+lane]; \
        F16x8 Af1=((const F16x8*)H0[(P_)^1])[1*64+lane]; \
        F16x8 Af2=((const F16x8*)H0[(P_)^1])[2*64+lane]; \
        F16x8 Af3=((const F16x8*)H0[(P_)^1])[3*64+lane]; \
        PRIO1(); \
        F32x4 a0=MFMA16(wf[0][0],Af0,ZED), a1=MFMA16(wf[1][0],Af0,ZED), a2=MFMA16(wf[2][0],Af0,ZED); \
        a0=MFMA16(wf[0][1],Af1,a0); a1=MFMA16(wf[1][1],Af1,a1); a2=MFMA16(wf[2][1],Af1,a2); \
        a0=MFMA16(wf[0][2],Af2,a0); a1=MFMA16(wf[1][2],Af2,a1); a2=MFMA16(wf[2][2],Af2,a2); \
        a0=MFMA16(wf[0][3],Af3,a0); a1=MFMA16(wf[1][3],Af3,a1); a2=MFMA16(wf[2][3],Af3,a2); \
        PRIO0(); \
        F16x4 v; v[0]=cfc_act3(a0[0],a1[0],a2[0]); v[1]=cfc_act3(a0[1],a1[1],a2[1]); \
        v[2]=cfc_act3(a0[2],a1[2],a2[2]); v[3]=cfc_act3(a0[3],a1[3],a2[3]); \
        *(F16x4*)&H0[P_][wk]=v; \
      } \
      if(dost && (I_)>=3 && (I_)<=1026){ \
        F16x8 sv=((const F16x8*)H2[(P_)^1])[q*16+bb]; \
        *(F16x8*)outPtr=sv; outPtr+=128; \
      } }while(0)
    for(int I2=0;I2<1028;I2+=2){
      L0_TICK(I2,0);   tick_barrier();
      L0_TICK(I2+1,1); tick_barrier();
    }
#undef L0_TICK
  } else {
    // ================= L2 triplet (+dt writer on w6) =================
    F16x8 wf[3][5];
    #pragma unroll
    for(int m=0;m<3;++m)
      #pragma unroll
      for(int kt=0;kt<5;++kt) wf[m][kt]=wsf[(201+(nb*3+m)*5+kt)*64+lane];
    const int wk=fidx(nb*16+g_l*4,b_l);   // nb<=2 -> n<=47 valid
    const bool dodt=(w==6);
#define L2_TICK(I_,P_) do{ \
      if(dodt && lane<16 && (I_)<=1022) H0[P_][fidx(124,lane)]=DTS[((I_)+1)*16+lane]; \
      if((I_)>=2 && (I_)<=1025){ \
        F16x8 Cf0=((const F16x8*)H1[(P_)^1])[0*64+lane]; \
        F16x8 Cf1=((const F16x8*)H1[(P_)^1])[1*64+lane]; \
        F16x8 Cf2=((const F16x8*)H1[(P_)^1])[2*64+lane]; \
        F16x8 Cf3=((const F16x8*)H2[(P_)^1])[0*64+lane]; \
        F16x8 Cf4=((const F16x8*)H2[(P_)^1])[1*64+lane]; \
        PRIO1(); \
        F32x4 a0=MFMA16(wf[0][0],Cf0,ZED), a1=MFMA16(wf[1][0],Cf0,ZED), a2=MFMA16(wf[2][0],Cf0,ZED); \
        a0=MFMA16(wf[0][1],Cf1,a0); a1=MFMA16(wf[1][1],Cf1,a1); a2=MFMA16(wf[2][1],Cf1,a2); \
        a0=MFMA16(wf[0][2],Cf2,a0); a1=MFMA16(wf[1][2],Cf2,a1); a2=MFMA16(wf[2][2],Cf2,a2); \
        a0=MFMA16(wf[0][3],Cf3,a0); a1=MFMA16(wf[1][3],Cf3,a1); a2=MFMA16(wf[2][3],Cf3,a2); \
        a0=MFMA16(wf[0][4],Cf4,a0); a1=MFMA16(wf[1][4],Cf4,a1); a2=MFMA16(wf[2][4],Cf4,a2); \
        PRIO0(); \
        F16x4 v; v[0]=cfc_act3(a0[0],a1[0],a2[0]); v[1]=cfc_act3(a0[1],a1[1],a2[1]); \
        v[2]=cfc_act3(a0[2],a1[2],a2[2]); v[3]=cfc_act3(a0[3],a1[3],a2[3]); \
        *(F16x4*)&H2[P_][wk]=v; \
      } }while(0)
    for(int I2=0;I2<1028;I2+=2){
      L2_TICK(I2,0);   tick_barrier();
      L2_TICK(I2+1,1); tick_barrier();
    }
#undef L2_TICK
  }
}

// ---------------- post: in-place d_out transform  h2(64 f16) -> y(32 f32) per (b,t) slot ----------------
__global__ __launch_bounds__(256) void cfc_ro(
    const float* __restrict__ Wo, const float* __restrict__ bo, float* __restrict__ outp)
{
  __shared__ h2v wT[1024];   // [kp][o]
  __shared__ float bs[32];
  int tid=threadIdx.x;
  for(int i=tid;i<1024;i+=256){ int kp=i>>5,o=i&31;
    h2v v; v[0]=(f16)Wo[o*64+2*kp]; v[1]=(f16)Wo[o*64+2*kp+1]; wT[i]=v; }
  if(tid<32) bs[tid]=bo[tid];
  __syncthreads();
  size_t s=(size_t)blockIdx.x*256+tid;      // 0..524287 = b*1024+t
  float* slot=outp+s*32;
  h2v x[32];
  #pragma unroll
  for(int r=0;r<8;++r) ((F16x8*)x)[r]=((const F16x8*)slot)[r];
  float y[32];
  #pragma unroll
  for(int o=0;o<32;++o){
    float acc=bs[o];
    #pragma unroll
    for(int kp=0;kp<32;++kp) acc=__builtin_amdgcn_fdot2(x[kp],wT[kp*32+o],acc,false);
    y[o]=acc;
  }
  #pragma unroll
  for(int r=0;r<8;++r) ((float4*)slot)[r]=((const float4*)y)[r];
}

extern "C" void kernel_launch(void* const* d_in, const int* in_sizes, int n_in,
                              void* d_out, int out_size, void* d_ws, size_t ws_size,
                              hipStream_t stream)
{
  (void)in_sizes; (void)n_in; (void)out_size; (void)ws_size;
  f16* ws=(f16*)d_ws;
  cfc_prep<<<66,256,0,stream>>>(
    (const float*)d_in[2],(const float*)d_in[3],(const float*)d_in[4],(const float*)d_in[5],
    (const float*)d_in[6],(const float*)d_in[7],(const float*)d_in[8],(const float*)d_in[9],
    (const int*)d_in[10],
    (const float*)d_in[11],(const float*)d_in[12],(const float*)d_in[13],(const float*)d_in[14],
    (const float*)d_in[15],(const float*)d_in[16],(const float*)d_in[17],(const float*)d_in[18],
    (const int*)d_in[19],
    (const float*)d_in[20],(const float*)d_in[21],(const float*)d_in[22],(const float*)d_in[23],
    (const float*)d_in[24],(const float*)d_in[25],(const float*)d_in[26],(const float*)d_in[27],
    (const int*)d_in[28],
    (const float*)d_in[29], ws);
  cfc_main<<<32,1024,0,stream>>>(
    (const float*)d_in[0],(const float*)d_in[1], ws, (float*)d_out);
  cfc_ro<<<2048,256,0,stream>>>(
    (const float*)d_in[29],(const float*)d_in[30],(float*)d_out);
}